// Round 8
// baseline (317.448 us; speedup 1.0000x reference)
//
#include <hip/hip_runtime.h>

#define T_SEQ 512
#define HID   50
#define NB    8           // batch rows per block (MFMA N=16: cols 0-7 = L0 batch, 8-15 = L1 batch)
#define BLK   832         // 13 waves; wave w owns L0 Mtile w AND L1 Mtile w

typedef float v4f  __attribute__((ext_vector_type(4)));
typedef _Float16 f16;
typedef f16  f16x8 __attribute__((ext_vector_type(8)));

// R18 = R17 (277us verified) + serial-chain trims in the epilogue + setprio:
//  (1) Montgomery q-products: d1d3d4 / d2d3d4(-2.885x) / p2*d4 computed DURING
//      rcp(p4)'s 16-cyc latency, so gf/giz/r3/go are each ONE mul from i4
//      (old: i4->i3->i2->gf 4-deep).  -8 cyc serial per step.
//  (2) csp state fold: recurrent state is csp = -2*log2e*cs; the tanh exp is
//      exp2(csp) directly (scale folded into giz pre-rcp).  -2-4 cyc serial.
//  (3) h = fmaf(go+go, r5, -go): kills the final serial mul.
//  (4) s_setprio(1) around epilogue+write: waves are drain-skewed (LDS pipe
//      serializes the 52 shared b128 reads), so tail-waves get issue priority
//      and reach the barrier sooner.
// Kept from R17: exp2-domain weights (g=2 row scaled 2*log2e), x-feed hoist,
// 13 waves, unroll x2 (compile-time tiles/pointers), boundary peel,
// dup-column layout (reg-to-reg CC select), CZ accumulator, 1 barrier/step.
// LDS tiles (f16, 8 k-tiles of 32): 0,1=hA buf0 (x@k62,1@k63); 2,3=hA buf1;
// 4,5=hB buf0; 6,7=hB buf1.  ODD s: read 0,1,6,7; L0->tile2, L1->tile4;
// x-feed tile3.  EVEN s: read 2,3,4,5; L0->tile0, L1->tile6; x-feed tile1.
// MFMA 16x16x32_f16: A[m=lane&15][k=(lane>>4)*8+j]; B[k=(lane>>4)*8+j][n=lane&15];
// C reg r = C[row=(lane>>4)*4+r][col=lane&15].  M layout: m=4u+g (gate-interleaved).

#define LOG2E 1.44269504f

__device__ __forceinline__ float exp2g(float x) {
#if __has_builtin(__builtin_amdgcn_exp2f)
    return __builtin_amdgcn_exp2f(x);
#else
    return __builtin_exp2f(x);
#endif
}

// loaders: weights/biases pre-scaled into exp2 domain (gate g=2 gets 2x)
__device__ __forceinline__ f16x8 ldA0(const float* __restrict__ Whh0,
                                      const float* __restrict__ Wih0,
                                      const float* __restrict__ bih0,
                                      const float* __restrict__ bhh0,
                                      int m, int kb) {
    const int u = m >> 2, g = m & 3;
    const float sc = (g == 2) ? (2.f * LOG2E) : LOG2E;
    f16x8 v;
    #pragma unroll
    for (int j = 0; j < 8; ++j) {
        const int k = kb + j;
        float f = 0.f;
        if (u < HID) {
            const int rho = g * HID + u;
            if (k < HID)      f = Whh0[rho * HID + k];
            else if (k == 62) f = Wih0[rho];
            else if (k == 63) f = bih0[rho] + bhh0[rho];
        }
        v[j] = (f16)(f * sc);
    }
    return v;
}

__device__ __forceinline__ f16x8 ldA1a(const float* __restrict__ Wih1,
                                       const float* __restrict__ bih1,
                                       const float* __restrict__ bhh1,
                                       int m, int kb) {
    const int u = m >> 2, g = m & 3;
    const float sc = (g == 2) ? (2.f * LOG2E) : LOG2E;
    f16x8 v;
    #pragma unroll
    for (int j = 0; j < 8; ++j) {
        const int k = kb + j;
        float f = 0.f;
        if (u < HID) {
            const int rho = g * HID + u;
            if (k < HID)      f = Wih1[rho * HID + k];
            else if (k == 63) f = bih1[rho] + bhh1[rho];
        }
        v[j] = (f16)(f * sc);
    }
    return v;
}

__device__ __forceinline__ f16x8 ldA1b(const float* __restrict__ Whh1,
                                       int m, int kb) {
    const int u = m >> 2, g = m & 3;
    const float sc = (g == 2) ? (2.f * LOG2E) : LOG2E;
    f16x8 v;
    #pragma unroll
    for (int j = 0; j < 8; ++j) {
        const int k = kb + j;
        float f = 0.f;
        if (u < HID && k < HID) f = Whh1[(g * HID + u) * HID + k];
        v[j] = (f16)(f * sc);
    }
    return v;
}

#define MFMA16(A, B, C) __builtin_amdgcn_mfma_f32_16x16x32_f16((A), (B), (C), 0, 0, 0)

// packed LSTM epilogue, exp2 domain.  State: csp = -2*log2e * cs.
// Montgomery batched rcp with q-products overlapped into rcp latency.
__device__ __forceinline__ float lstm_epi(const v4f CC, float& csp) {
    const float e1 = exp2g(-CC.x);
    const float e2 = exp2g(-CC.y);
    const float e3 = exp2g(-CC.z);          // z-row pre-scaled by 2*log2e
    const float e4 = exp2g(-CC.w);
    const float d1 = 1.f + e1, d2 = 1.f + e2, d3 = 1.f + e3, d4 = 1.f + e4;
    const float p2 = d1 * d2, p3 = p2 * d3, p4 = p3 * d4;
    const float i4 = __builtin_amdgcn_rcpf(p4);
    // q-products: issue during the rcp's latency (no serial cost)
    const float t34 = d3 * d4;
    const float A1z = (-2.f * LOG2E) * (d2 * t34);   // -> giz = -2.885/d1
    const float A2  = d1 * t34;                       // -> gf  = 1/d2
    const float A3  = p2 * d4;                        // -> r3  = 1/d3
    // post-rcp: each factor ONE mul from i4
    const float go  = p3 * i4;                        // 1/d4
    const float gf  = A2 * i4;
    const float r3  = A3 * i4;
    const float giz = A1z * i4;
    const float gg  = fmaf(2.f, r3, -1.f);            // tanh(z)
    csp = fmaf(gf, csp, giz * gg);                    // csp = -2.885*cs
    const float e5 = exp2g(csp);
    const float r5 = __builtin_amdgcn_rcpf(1.f + e5);
    const float go2 = go + go;                        // issues during rcp#2
    return fmaf(go2, r5, -go);                        // go * tanh(cs)
}

__global__ __launch_bounds__(BLK, 1)
void lstm2_mfma(const float* __restrict__ x,
                const float* __restrict__ Wih0,
                const float* __restrict__ Whh0,
                const float* __restrict__ bih0,
                const float* __restrict__ bhh0,
                const float* __restrict__ Wih1,
                const float* __restrict__ Whh1,
                const float* __restrict__ bih1,
                const float* __restrict__ bhh1,
                const float* __restrict__ Wfc,
                const float* __restrict__ bfc,
                float* __restrict__ out)
{
    __shared__ __align__(16) f16 BPH [8 * 64 * 8];   // 8,192 B: B frags (dbuf hA/hB, dup cols)
    __shared__ f16   xs16[NB][T_SEQ];                // 8,192 B: staged x (f16)
    __shared__ float hfin[HID][NB];                  // 1,600 B: final hB fp32

    const int tid  = threadIdx.x;
    const int w    = tid >> 6;                       // 0..12 = Mtile index (both layers)
    const int lane = tid & 63;
    const int n16  = lane & 15;
    const int quad = lane >> 4;
    const int bb0  = blockIdx.x * NB;

    const float* xg = x + (long)bb0 * T_SEQ;

    // ---- one-time: zero B frags; stage x -> f16 LDS ----
    for (int i = tid; i < 8 * 64 * 8; i += BLK) BPH[i] = (f16)0.f;
    for (int i = tid; i < NB * T_SEQ; i += BLK) {
        const int n = i >> 9, tt = i & (T_SEQ - 1);
        xs16[n][tt] = (f16)xg[n * T_SEQ + tt];
    }

    // ---- one-time: this wave's weights for BOTH layers, Mtile w ----
    const int m   = w * 16 + n16;
    const int kb0 = quad * 8, kb1 = 32 + quad * 8;
    const f16x8 a0 = ldA0(Whh0, Wih0, bih0, bhh0, m, kb0);   // L0: [Whh0|x|b]
    const f16x8 a1 = ldA0(Whh0, Wih0, bih0, bhh0, m, kb1);
    const f16x8 v0 = ldA1a(Wih1, bih1, bhh1, m, kb0);        // L1: hA-side [Wih1|b]
    const f16x8 v1 = ldA1a(Wih1, bih1, bhh1, m, kb1);
    const f16x8 v2 = ldA1b(Whh1, m, kb0);                    // L1: hB-side Whh1
    const f16x8 v3 = ldA1b(Whh1, m, kb1);

    __syncthreads();
    // "1.0" bias (k=63) in both hA bufs, BOTH column halves; x(0) likewise
    if (tid < NB) {
        BPH[(1 * 64 + 48 + tid) * 8 + 7] = (f16)1.f;
        BPH[(1 * 64 + 56 + tid) * 8 + 7] = (f16)1.f;
        BPH[(3 * 64 + 48 + tid) * 8 + 7] = (f16)1.f;
        BPH[(3 * 64 + 56 + tid) * 8 + 7] = (f16)1.f;
        BPH[(3 * 64 + 48 + tid) * 8 + 6] = xs16[tid][0];
        BPH[(3 * 64 + 56 + tid) * 8 + 6] = xs16[tid][0];
    }
    __syncthreads();

    // per-lane cell state: cols 0-7 track L0 cell (u_, n16), cols 8-15 track
    // L1 cell (u_, n16-8).  u_ fixed per lane all steps.  State: csp=-2.885*cs.
    const int  u_    = w * 4 + quad;
    const bool isl0  = (n16 < 8);
    const bool valid = (u_ < HID);
    // step-invariant write pointers (dup-column: [0] and [64] elems = +0/+128B)
    const int  wbase = (((u_ & 31) >> 3) * 16 + (n16 & 7)) * 8 + (u_ & 7) + (u_ >> 5) * 512;
    f16* const pwOdd  = &BPH[wbase + (isl0 ? 2 : 4) * 512];  // ODD s : L0 tile2, L1 tile4
    f16* const pwEven = &BPH[wbase + (isl0 ? 0 : 6) * 512];  // EVEN s: L0 tile0, L1 tile6
    float csp = 0.f;
    const f16x8* BPF = (const f16x8*)BPH;
    const v4f CZ = {0.f, 0.f, 0.f, 0.f};            // loop-invariant zero accumulator

    // ---- peeled s = 0: L0 only (reads tiles 2,3; writes tile0; x-feed tile1) ----
    {
        const f16x8 B0 = BPF[2 * 64 + lane];
        const f16x8 B1 = BPF[3 * 64 + lane];
        v4f D = MFMA16(a0, B0, CZ);  D = MFMA16(a1, B1, D);
        const float csp_sav = csp;
        const float hh = lstm_epi(D, csp);
        if (!isl0) csp = csp_sav;                    // L1 lanes: no update at s=0
        if (valid && isl0) { const f16 hv = (f16)hh; pwEven[0] = hv; pwEven[64] = hv; }
        if (w == 0 && lane < NB) {
            const f16 xv = xs16[lane][1];
            BPH[(1 * 64 + 48 + lane) * 8 + 6] = xv;
            BPH[(1 * 64 + 56 + lane) * 8 + 6] = xv;
        }
        __syncthreads();
    }

    // body step: both layers active, compile-time tiles/pointers.
    // x prefetch issues with the B-reads; epilogue+write wrapped in setprio(1).
#define STEP(TA, TB, PW, XT, XS, DOX) {                                       \
        const f16x8 B0 = BPF[(TA)     * 64 + lane];                           \
        const f16x8 B1 = BPF[(TA + 1) * 64 + lane];                           \
        const f16x8 B2 = BPF[(TB)     * 64 + lane];                           \
        const f16x8 B3 = BPF[(TB + 1) * 64 + lane];                           \
        const bool dox = (DOX) && w == 0 && lane < NB;                        \
        const f16 xv = dox ? xs16[lane][(XS)] : (f16)0.f;                     \
        v4f D = MFMA16(a0, B0, CZ);  D = MFMA16(a1, B1, D);                   \
        v4f E = MFMA16(v0, B0, CZ);  E = MFMA16(v1, B1, E);                   \
        E = MFMA16(v2, B2, E);       E = MFMA16(v3, B3, E);                   \
        v4f CC;                                                               \
        CC.x = isl0 ? D.x : E.x;  CC.y = isl0 ? D.y : E.y;                    \
        CC.z = isl0 ? D.z : E.z;  CC.w = isl0 ? D.w : E.w;                    \
        __builtin_amdgcn_s_setprio(1);                                        \
        const float hh = lstm_epi(CC, csp);                                   \
        if (valid) { const f16 hv = (f16)hh; (PW)[0] = hv; (PW)[64] = hv; }   \
        if (dox) {                                                            \
            BPH[((XT) * 64 + 48 + lane) * 8 + 6] = xv;                        \
            BPH[((XT) * 64 + 56 + lane) * 8 + 6] = xv;                        \
        }                                                                     \
        __builtin_amdgcn_s_setprio(0);                                        \
        __syncthreads(); }

    // ---- main: s = 1..510 in ODD/EVEN pairs, then s = 511 (no x-feed) ----
    #pragma clang loop unroll(disable)
    for (int s = 1; s < 511; s += 2) {
        STEP(0, 6, pwOdd,  3, s + 1, true)    // ODD s : read 0,1,6,7
        STEP(2, 4, pwEven, 1, s + 2, true)    // EVEN s: read 2,3,4,5
    }
    STEP(0, 6, pwOdd, 3, 0, false)            // s = 511

    // ---- peeled s = 512: L1 finish only (reads tiles 2,3,4,5) ----
    {
        const f16x8 B0 = BPF[2 * 64 + lane];
        const f16x8 B1 = BPF[3 * 64 + lane];
        const f16x8 B2 = BPF[4 * 64 + lane];
        const f16x8 B3 = BPF[5 * 64 + lane];
        v4f E = MFMA16(v0, B0, CZ);  E = MFMA16(v1, B1, E);
        E = MFMA16(v2, B2, E);       E = MFMA16(v3, B3, E);
        const float hh = lstm_epi(E, csp);
        if (!isl0 && valid) hfin[u_][n16 & 7] = hh;
        __syncthreads();
    }

    // ---- classifier: out[n][c] = hB[n] . Wfc[c] + bfc[c] ----
    if (tid < NB * 2) {
        const int nn = tid >> 1, c = tid & 1;
        float acc = bfc[c];
        #pragma unroll
        for (int u = 0; u < HID; ++u)
            acc = fmaf(Wfc[c * HID + u], hfin[u][nn], acc);
        out[(bb0 + nn) * 2 + c] = acc;
    }
}

extern "C" void kernel_launch(void* const* d_in, const int* in_sizes, int n_in,
                              void* d_out, int out_size, void* d_ws, size_t ws_size,
                              hipStream_t stream) {
    const float* x    = (const float*)d_in[0];
    const float* Wih0 = (const float*)d_in[1];
    const float* Whh0 = (const float*)d_in[2];
    const float* bih0 = (const float*)d_in[3];
    const float* bhh0 = (const float*)d_in[4];
    const float* Wih1 = (const float*)d_in[5];
    const float* Whh1 = (const float*)d_in[6];
    const float* bih1 = (const float*)d_in[7];
    const float* bhh1 = (const float*)d_in[8];
    const float* Wfc  = (const float*)d_in[9];
    const float* bfc  = (const float*)d_in[10];
    float* out = (float*)d_out;

    const int B = in_sizes[0] / T_SEQ;   // D == 1
    const int grid = B / NB;             // 2048/8 = 256 blocks -> 1 block/CU

    hipLaunchKernelGGL(lstm2_mfma, dim3(grid), dim3(BLK), 0, stream,
                       x, Wih0, Whh0, bih0, bhh0, Wih1, Whh1, bih1, bhh1,
                       Wfc, bfc, out);
}

// Round 9
// 312.015 us; speedup vs baseline: 1.0174x; 1.0174x over previous
//
#include <hip/hip_runtime.h>

#define T_SEQ 512
#define HID   50
#define NB    8           // batch rows per block (MFMA N=16: cols 0-7 = L0 batch, 8-15 = L1 batch)
#define BLK   832         // 13 waves; wave w owns L0 Mtile w AND L1 Mtile w

typedef float v4f  __attribute__((ext_vector_type(4)));
typedef _Float16 f16;
typedef f16  f16x8 __attribute__((ext_vector_type(8)));

// R19 = R17 (277us verified best) + the one issue-neutral piece of R18:
//  h = fmaf(go+go, r5, -go)  (go2 issues in rcp#2's shadow; add replaces mul
//  -> 0 extra issue, -1 serial op).  R18's q-product restructure (+3 muls
//  issue for -4cyc serial) and setprio (null-to-negative on lockstep) are
//  REVERTED -- this kernel is issue-bound in the epilogue phase (R18 lesson).
// Model closure: step=1296cyc = VALU issue ~660/SIMD (51%) + LDS drain ~620
// (52 shared b128 + writes), serialized by the per-step phase-lock.  Reads
// can't drop below 4/wave (L1 spans 102 k-slots); trans (5 exp2+2 rcp) is the
// LSTM floor; R14/R16 restructures both lost.  If this round reproduces
// ~277us the structure is at its floor.
// Kept from R17: exp2-domain weights (g=2 row scaled 2*log2e), x-feed hoist,
// 13 waves, unroll x2 (compile-time tiles/pointers), boundary peel,
// dup-column layout (reg-to-reg CC select), CZ accumulator, 1 barrier/step.
// LDS tiles (f16, 8 k-tiles of 32): 0,1=hA buf0 (x@k62,1@k63); 2,3=hA buf1;
// 4,5=hB buf0; 6,7=hB buf1.  ODD s: read 0,1,6,7; L0->tile2, L1->tile4;
// x-feed tile3.  EVEN s: read 2,3,4,5; L0->tile0, L1->tile6; x-feed tile1.
// MFMA 16x16x32_f16: A[m=lane&15][k=(lane>>4)*8+j]; B[k=(lane>>4)*8+j][n=lane&15];
// C reg r = C[row=(lane>>4)*4+r][col=lane&15].  M layout: m=4u+g (gate-interleaved).

#define LOG2E 1.44269504f

__device__ __forceinline__ float exp2g(float x) {
#if __has_builtin(__builtin_amdgcn_exp2f)
    return __builtin_amdgcn_exp2f(x);
#else
    return __builtin_exp2f(x);
#endif
}

// loaders: weights/biases pre-scaled into exp2 domain (gate g=2 gets 2x)
__device__ __forceinline__ f16x8 ldA0(const float* __restrict__ Whh0,
                                      const float* __restrict__ Wih0,
                                      const float* __restrict__ bih0,
                                      const float* __restrict__ bhh0,
                                      int m, int kb) {
    const int u = m >> 2, g = m & 3;
    const float sc = (g == 2) ? (2.f * LOG2E) : LOG2E;
    f16x8 v;
    #pragma unroll
    for (int j = 0; j < 8; ++j) {
        const int k = kb + j;
        float f = 0.f;
        if (u < HID) {
            const int rho = g * HID + u;
            if (k < HID)      f = Whh0[rho * HID + k];
            else if (k == 62) f = Wih0[rho];
            else if (k == 63) f = bih0[rho] + bhh0[rho];
        }
        v[j] = (f16)(f * sc);
    }
    return v;
}

__device__ __forceinline__ f16x8 ldA1a(const float* __restrict__ Wih1,
                                       const float* __restrict__ bih1,
                                       const float* __restrict__ bhh1,
                                       int m, int kb) {
    const int u = m >> 2, g = m & 3;
    const float sc = (g == 2) ? (2.f * LOG2E) : LOG2E;
    f16x8 v;
    #pragma unroll
    for (int j = 0; j < 8; ++j) {
        const int k = kb + j;
        float f = 0.f;
        if (u < HID) {
            const int rho = g * HID + u;
            if (k < HID)      f = Wih1[rho * HID + k];
            else if (k == 63) f = bih1[rho] + bhh1[rho];
        }
        v[j] = (f16)(f * sc);
    }
    return v;
}

__device__ __forceinline__ f16x8 ldA1b(const float* __restrict__ Whh1,
                                       int m, int kb) {
    const int u = m >> 2, g = m & 3;
    const float sc = (g == 2) ? (2.f * LOG2E) : LOG2E;
    f16x8 v;
    #pragma unroll
    for (int j = 0; j < 8; ++j) {
        const int k = kb + j;
        float f = 0.f;
        if (u < HID && k < HID) f = Whh1[(g * HID + u) * HID + k];
        v[j] = (f16)(f * sc);
    }
    return v;
}

#define MFMA16(A, B, C) __builtin_amdgcn_mfma_f32_16x16x32_f16((A), (B), (C), 0, 0, 0)

// packed LSTM epilogue, exp2 domain (R17 chain), Montgomery batched rcp.
// Tail: h = fmaf(go+go, r5, -go) -- go2 issues under rcp#2's latency.
__device__ __forceinline__ float lstm_epi(const v4f CC, float& cs) {
    const float e1 = exp2g(-CC.x);
    const float e2 = exp2g(-CC.y);
    const float e3 = exp2g(-CC.z);          // z-row pre-scaled by 2*log2e
    const float e4 = exp2g(-CC.w);
    const float d1 = 1.f + e1, d2 = 1.f + e2, d3 = 1.f + e3, d4 = 1.f + e4;
    const float p2 = d1 * d2, p3 = p2 * d3, p4 = p3 * d4;
    const float i4 = __builtin_amdgcn_rcpf(p4);
    const float go = i4 * p3;                 /* 1/d4 */
    const float i3 = i4 * d4;
    const float r3 = i3 * p2;                 /* 1/d3 */
    const float i2 = i3 * d3;
    const float gf = i2 * d1;                 /* 1/d2 */
    const float gi = i2 * d2;                 /* 1/d1 */
    const float gg = fmaf(2.f, r3, -1.f);
    cs = fmaf(gf, cs, gi * gg);
    const float e5 = exp2g(-2.88539008f * cs);
    const float r5 = __builtin_amdgcn_rcpf(1.f + e5);
    const float go2 = go + go;                // issues during rcp#2
    return fmaf(go2, r5, -go);                // go * tanh(cs)
}

__global__ __launch_bounds__(BLK, 1)
void lstm2_mfma(const float* __restrict__ x,
                const float* __restrict__ Wih0,
                const float* __restrict__ Whh0,
                const float* __restrict__ bih0,
                const float* __restrict__ bhh0,
                const float* __restrict__ Wih1,
                const float* __restrict__ Whh1,
                const float* __restrict__ bih1,
                const float* __restrict__ bhh1,
                const float* __restrict__ Wfc,
                const float* __restrict__ bfc,
                float* __restrict__ out)
{
    __shared__ __align__(16) f16 BPH [8 * 64 * 8];   // 8,192 B: B frags (dbuf hA/hB, dup cols)
    __shared__ f16   xs16[NB][T_SEQ];                // 8,192 B: staged x (f16)
    __shared__ float hfin[HID][NB];                  // 1,600 B: final hB fp32

    const int tid  = threadIdx.x;
    const int w    = tid >> 6;                       // 0..12 = Mtile index (both layers)
    const int lane = tid & 63;
    const int n16  = lane & 15;
    const int quad = lane >> 4;
    const int bb0  = blockIdx.x * NB;

    const float* xg = x + (long)bb0 * T_SEQ;

    // ---- one-time: zero B frags; stage x -> f16 LDS ----
    for (int i = tid; i < 8 * 64 * 8; i += BLK) BPH[i] = (f16)0.f;
    for (int i = tid; i < NB * T_SEQ; i += BLK) {
        const int n = i >> 9, tt = i & (T_SEQ - 1);
        xs16[n][tt] = (f16)xg[n * T_SEQ + tt];
    }

    // ---- one-time: this wave's weights for BOTH layers, Mtile w ----
    const int m   = w * 16 + n16;
    const int kb0 = quad * 8, kb1 = 32 + quad * 8;
    const f16x8 a0 = ldA0(Whh0, Wih0, bih0, bhh0, m, kb0);   // L0: [Whh0|x|b]
    const f16x8 a1 = ldA0(Whh0, Wih0, bih0, bhh0, m, kb1);
    const f16x8 v0 = ldA1a(Wih1, bih1, bhh1, m, kb0);        // L1: hA-side [Wih1|b]
    const f16x8 v1 = ldA1a(Wih1, bih1, bhh1, m, kb1);
    const f16x8 v2 = ldA1b(Whh1, m, kb0);                    // L1: hB-side Whh1
    const f16x8 v3 = ldA1b(Whh1, m, kb1);

    __syncthreads();
    // "1.0" bias (k=63) in both hA bufs, BOTH column halves; x(0) likewise
    if (tid < NB) {
        BPH[(1 * 64 + 48 + tid) * 8 + 7] = (f16)1.f;
        BPH[(1 * 64 + 56 + tid) * 8 + 7] = (f16)1.f;
        BPH[(3 * 64 + 48 + tid) * 8 + 7] = (f16)1.f;
        BPH[(3 * 64 + 56 + tid) * 8 + 7] = (f16)1.f;
        BPH[(3 * 64 + 48 + tid) * 8 + 6] = xs16[tid][0];
        BPH[(3 * 64 + 56 + tid) * 8 + 6] = xs16[tid][0];
    }
    __syncthreads();

    // per-lane cell state: cols 0-7 track L0 cell (u_, n16), cols 8-15 track
    // L1 cell (u_, n16-8).  u_ fixed per lane for all steps.
    const int  u_    = w * 4 + quad;
    const bool isl0  = (n16 < 8);
    const bool valid = (u_ < HID);
    // step-invariant write pointers (dup-column: [0] and [64] elems = +0/+128B)
    const int  wbase = (((u_ & 31) >> 3) * 16 + (n16 & 7)) * 8 + (u_ & 7) + (u_ >> 5) * 512;
    f16* const pwOdd  = &BPH[wbase + (isl0 ? 2 : 4) * 512];  // ODD s : L0 tile2, L1 tile4
    f16* const pwEven = &BPH[wbase + (isl0 ? 0 : 6) * 512];  // EVEN s: L0 tile0, L1 tile6
    float cs = 0.f;
    const f16x8* BPF = (const f16x8*)BPH;
    const v4f CZ = {0.f, 0.f, 0.f, 0.f};            // loop-invariant zero accumulator

    // ---- peeled s = 0: L0 only (reads tiles 2,3; writes tile0; x-feed tile1) ----
    {
        const f16x8 B0 = BPF[2 * 64 + lane];
        const f16x8 B1 = BPF[3 * 64 + lane];
        v4f D = MFMA16(a0, B0, CZ);  D = MFMA16(a1, B1, D);
        const float cs_sav = cs;
        const float hh = lstm_epi(D, cs);
        if (!isl0) cs = cs_sav;                      // L1 lanes: no update at s=0
        if (valid && isl0) { const f16 hv = (f16)hh; pwEven[0] = hv; pwEven[64] = hv; }
        if (w == 0 && lane < NB) {
            const f16 xv = xs16[lane][1];
            BPH[(1 * 64 + 48 + lane) * 8 + 6] = xv;
            BPH[(1 * 64 + 56 + lane) * 8 + 6] = xv;
        }
        __syncthreads();
    }

    // body step: both layers active, compile-time tiles/pointers.
    // x prefetch issues with the B-reads (same lgkm queue); write stays late.
#define STEP(TA, TB, PW, XT, XS, DOX) {                                       \
        const f16x8 B0 = BPF[(TA)     * 64 + lane];                           \
        const f16x8 B1 = BPF[(TA + 1) * 64 + lane];                           \
        const f16x8 B2 = BPF[(TB)     * 64 + lane];                           \
        const f16x8 B3 = BPF[(TB + 1) * 64 + lane];                           \
        const bool dox = (DOX) && w == 0 && lane < NB;                        \
        const f16 xv = dox ? xs16[lane][(XS)] : (f16)0.f;                     \
        v4f D = MFMA16(a0, B0, CZ);  D = MFMA16(a1, B1, D);                   \
        v4f E = MFMA16(v0, B0, CZ);  E = MFMA16(v1, B1, E);                   \
        E = MFMA16(v2, B2, E);       E = MFMA16(v3, B3, E);                   \
        v4f CC;                                                               \
        CC.x = isl0 ? D.x : E.x;  CC.y = isl0 ? D.y : E.y;                    \
        CC.z = isl0 ? D.z : E.z;  CC.w = isl0 ? D.w : E.w;                    \
        const float hh = lstm_epi(CC, cs);                                    \
        if (valid) { const f16 hv = (f16)hh; (PW)[0] = hv; (PW)[64] = hv; }   \
        if (dox) {                                                            \
            BPH[((XT) * 64 + 48 + lane) * 8 + 6] = xv;                        \
            BPH[((XT) * 64 + 56 + lane) * 8 + 6] = xv;                        \
        }                                                                     \
        __syncthreads(); }

    // ---- main: s = 1..510 in ODD/EVEN pairs, then s = 511 (no x-feed) ----
    #pragma clang loop unroll(disable)
    for (int s = 1; s < 511; s += 2) {
        STEP(0, 6, pwOdd,  3, s + 1, true)    // ODD s : read 0,1,6,7
        STEP(2, 4, pwEven, 1, s + 2, true)    // EVEN s: read 2,3,4,5
    }
    STEP(0, 6, pwOdd, 3, 0, false)            // s = 511

    // ---- peeled s = 512: L1 finish only (reads tiles 2,3,4,5) ----
    {
        const f16x8 B0 = BPF[2 * 64 + lane];
        const f16x8 B1 = BPF[3 * 64 + lane];
        const f16x8 B2 = BPF[4 * 64 + lane];
        const f16x8 B3 = BPF[5 * 64 + lane];
        v4f E = MFMA16(v0, B0, CZ);  E = MFMA16(v1, B1, E);
        E = MFMA16(v2, B2, E);       E = MFMA16(v3, B3, E);
        const float hh = lstm_epi(E, cs);
        if (!isl0 && valid) hfin[u_][n16 & 7] = hh;
        __syncthreads();
    }

    // ---- classifier: out[n][c] = hB[n] . Wfc[c] + bfc[c] ----
    if (tid < NB * 2) {
        const int nn = tid >> 1, c = tid & 1;
        float acc = bfc[c];
        #pragma unroll
        for (int u = 0; u < HID; ++u)
            acc = fmaf(Wfc[c * HID + u], hfin[u][nn], acc);
        out[(bb0 + nn) * 2 + c] = acc;
    }
}

extern "C" void kernel_launch(void* const* d_in, const int* in_sizes, int n_in,
                              void* d_out, int out_size, void* d_ws, size_t ws_size,
                              hipStream_t stream) {
    const float* x    = (const float*)d_in[0];
    const float* Wih0 = (const float*)d_in[1];
    const float* Whh0 = (const float*)d_in[2];
    const float* bih0 = (const float*)d_in[3];
    const float* bhh0 = (const float*)d_in[4];
    const float* Wih1 = (const float*)d_in[5];
    const float* Whh1 = (const float*)d_in[6];
    const float* bih1 = (const float*)d_in[7];
    const float* bhh1 = (const float*)d_in[8];
    const float* Wfc  = (const float*)d_in[9];
    const float* bfc  = (const float*)d_in[10];
    float* out = (float*)d_out;

    const int B = in_sizes[0] / T_SEQ;   // D == 1
    const int grid = B / NB;             // 2048/8 = 256 blocks -> 1 block/CU

    hipLaunchKernelGGL(lstm2_mfma, dim3(grid), dim3(BLK), 0, stream,
                       x, Wih0, Whh0, bih0, bhh0, Wih1, Whh1, bih1, bhh1,
                       Wfc, bfc, out);
}